// Round 3
// baseline (229.153 us; speedup 1.0000x reference)
//
#include <hip/hip_runtime.h>

#define HW (256*256)
#define NKPT 68
#define NB 128

typedef float v4f __attribute__((ext_vector_type(4)));

__device__ inline void inv3x3(const double m[9], double inv[9], double* detOut) {
    double c00 =  m[4]*m[8] - m[5]*m[7];
    double c01 = -(m[3]*m[8] - m[5]*m[6]);
    double c02 =  m[3]*m[7] - m[4]*m[6];
    double det = m[0]*c00 + m[1]*c01 + m[2]*c02;
    double id = 1.0 / det;
    inv[0] = c00 * id;
    inv[1] = (m[2]*m[7] - m[1]*m[8]) * id;
    inv[2] = (m[1]*m[5] - m[2]*m[4]) * id;
    inv[3] = c01 * id;
    inv[4] = (m[0]*m[8] - m[2]*m[6]) * id;
    inv[5] = (m[2]*m[3] - m[0]*m[5]) * id;
    inv[6] = c02 * id;
    inv[7] = (m[1]*m[6] - m[0]*m[7]) * id;
    inv[8] = (m[0]*m[4] - m[1]*m[3]) * id;
    *detOut = det;
}

// Single fused kernel. 2048 blocks = 128 batches x 16 slabs.
// b = blockIdx & 127 so all 16 blocks of a batch share blockIdx%8 -> same XCD L2
// (keypoint gather lines fetched from HBM once per batch, L2-hit for the rest).
// Every block redundantly computes its batch's (R,t): gather 68 kpts, reduce 17
// sufficient stats, thread 0 runs det-scaled fp64 Newton polar iteration
// (== SVD polar factor, R = polar(Hm)^T) — identical math to the previous
// 2-kernel version, so per-batch results are bit-identical and deterministic.
// The ~2-3 us serial Newton head overlaps across resident blocks; streaming
// phase then applies R,t to this block's 4096-px slab at HBM rate.
__global__ __launch_bounds__(256) void fused_kernel(
    const float* __restrict__ Offset,
    const float* __restrict__ Posmap,
    const float* __restrict__ meanp,
    const int*   __restrict__ uv,
    float* __restrict__ out)
{
    const int b    = blockIdx.x & 127;
    const int slab = blockIdx.x >> 7;
    const int tid  = threadIdx.x;

    __shared__ double red[17][NKPT];
    __shared__ double res[17];
    __shared__ float  rtS[12];

    const size_t bbase = (size_t)b * 3 * HW;

    // ---- phase 1: sufficient statistics over the 68 keypoints ----
    if (tid < NKPT) {
        const int r  = uv[2*tid],   c  = uv[2*tid+1];
        const int r0 = uv[0],       c0 = uv[1];
        const int p  = r  * 256 + c;
        const int p0 = r0 * 256 + c0;
        const float* offB = Offset + bbase;
        const float* posB = Posmap + bbase;
        double s[3], d[3], s0[3], d0[3];
        #pragma unroll
        for (int k = 0; k < 3; ++k) {
            s[k]  = (double)offB[k*HW + p ] * 6.0 + (double)meanp[k*HW + p ];
            d[k]  = (double)posB[k*HW + p ];
            s0[k] = (double)offB[k*HW + p0] * 6.0 + (double)meanp[k*HW + p0];
            d0[k] = (double)posB[k*HW + p0];
        }
        int q = 0;
        #pragma unroll
        for (int k = 0; k < 3; ++k) red[q++][tid] = s[k];
        #pragma unroll
        for (int k = 0; k < 3; ++k) red[q++][tid] = d[k];
        #pragma unroll
        for (int i = 0; i < 3; ++i)
            #pragma unroll
            for (int j = 0; j < 3; ++j) red[q++][tid] = s[i] * d[j];
        double ns2 = 0.0, nd2 = 0.0;
        #pragma unroll
        for (int k = 0; k < 3; ++k) {
            double e = s[k] - s0[k]; ns2 += e*e;
            double f = d[k] - d0[k]; nd2 += f*f;
        }
        red[q++][tid] = (ns2 > 0.0) ? sqrt(ns2) : 0.0;  // _safe_norm
        red[q++][tid] = (nd2 > 0.0) ? sqrt(nd2) : 0.0;
    }
    __syncthreads();
    if (tid < 17) {
        double acc = 0.0;
        for (int i = 0; i < NKPT; ++i) acc += red[tid][i];
        res[tid] = acc;
    }
    __syncthreads();

    // ---- phase 2: thread 0 solves the 3x3 polar problem ----
    if (tid == 0) {
        const double sumS[3] = {res[0], res[1], res[2]};
        const double sumD[3] = {res[3], res[4], res[5]};
        double cross[9];
        #pragma unroll
        for (int k = 0; k < 9; ++k) cross[k] = res[6+k];
        const double s1 = res[15], s2 = res[16];
        const double scale = s2 / s1;
        double mS[3], mD[3];
        #pragma unroll
        for (int k = 0; k < 3; ++k) { mS[k] = sumS[k] / NKPT; mD[k] = sumD[k] / NKPT; }
        // Hm = (A - meanA)^T (dst - meanDst),  A = scale*src
        double Wm[9];
        #pragma unroll
        for (int i = 0; i < 3; ++i)
            #pragma unroll
            for (int j = 0; j < 3; ++j)
                Wm[i*3+j] = scale * (cross[i*3+j] - (double)NKPT * mS[i] * mD[j]);
        // Newton polar iteration: W -> 0.5*(g^-1 * W + g * W^-T), g = |det W|^(1/3).
        for (int it = 0; it < 8; ++it) {
            double inv[9], det;
            inv3x3(Wm, inv, &det);
            double g  = cbrt(fabs(det));
            double gi = 1.0 / g;
            double Wn[9];
            #pragma unroll
            for (int r = 0; r < 3; ++r)
                #pragma unroll
                for (int c = 0; c < 3; ++c)
                    Wn[r*3+c] = 0.5 * (gi * Wm[r*3+c] + g * inv[c*3+r]);
            #pragma unroll
            for (int k = 0; k < 9; ++k) Wm[k] = Wn[k];
        }
        // R[e][d] = scale * Wm[d][e]  (R = V U^T = polar(Hm)^T)
        #pragma unroll
        for (int e = 0; e < 3; ++e)
            #pragma unroll
            for (int d = 0; d < 3; ++d)
                rtS[e*3+d] = (float)(scale * Wm[d*3+e]);
        #pragma unroll
        for (int e = 0; e < 3; ++e) {
            double acc = mD[e];
            #pragma unroll
            for (int d = 0; d < 3; ++d) acc -= scale * mS[d] * Wm[d*3+e];
            rtS[9+e] = (float)acc;
        }
    }
    __syncthreads();

    // ---- phase 3: streaming apply on this block's 4096-px slab ----
    const float r00 = rtS[0], r01 = rtS[1], r02 = rtS[2];
    const float r10 = rtS[3], r11 = rtS[4], r12 = rtS[5];
    const float r20 = rtS[6], r21 = rtS[7], r22 = rtS[8];
    const float t0  = rtS[9], t1  = rtS[10], t2 = rtS[11];

    const int p0 = slab * 4096 + tid * 4;   // 4 groups, stride 1024 px

    v4f a[3][4], m[3][4];
    #pragma unroll
    for (int g = 0; g < 4; ++g) {
        const int p = p0 + g * 1024;
        #pragma unroll
        for (int ch = 0; ch < 3; ++ch)
            a[ch][g] = __builtin_nontemporal_load((const v4f*)(Offset + bbase + (size_t)ch * HW + p));
    }
    #pragma unroll
    for (int g = 0; g < 4; ++g) {
        const int p = p0 + g * 1024;
        #pragma unroll
        for (int ch = 0; ch < 3; ++ch)
            m[ch][g] = *(const v4f*)(meanp + (size_t)ch * HW + p);
    }

    #pragma unroll
    for (int g = 0; g < 4; ++g) {
        const int p = p0 + g * 1024;
        v4f o0, o1, o2;
        #pragma unroll
        for (int L = 0; L < 4; ++L) {
            float x = fmaf(6.0f, a[0][g][L], m[0][g][L]);
            float y = fmaf(6.0f, a[1][g][L], m[1][g][L]);
            float z = fmaf(6.0f, a[2][g][L], m[2][g][L]);
            o0[L] = fmaf(r00, x, fmaf(r01, y, fmaf(r02, z, t0)));
            o1[L] = fmaf(r10, x, fmaf(r11, y, fmaf(r12, z, t1)));
            o2[L] = fmaf(r20, x, fmaf(r21, y, fmaf(r22, z, t2)));
        }
        __builtin_nontemporal_store(o0, (v4f*)(out + bbase + 0*HW + p));
        __builtin_nontemporal_store(o1, (v4f*)(out + bbase + 1*HW + p));
        __builtin_nontemporal_store(o2, (v4f*)(out + bbase + 2*HW + p));
    }
}

extern "C" void kernel_launch(void* const* d_in, const int* in_sizes, int n_in,
                              void* d_out, int out_size, void* d_ws, size_t ws_size,
                              hipStream_t stream) {
    const float* Offset = (const float*)d_in[0];
    const float* Posmap = (const float*)d_in[1];
    const float* meanp  = (const float*)d_in[2];
    const int*   uv     = (const int*)d_in[3];
    float* out = (float*)d_out;

    fused_kernel<<<NB * 16, 256, 0, stream>>>(Offset, Posmap, meanp, uv, out);
}

// Round 4
// 228.458 us; speedup vs baseline: 1.0030x; 1.0030x over previous
//
#include <hip/hip_runtime.h>

#define HW (256*256)
#define NKPT 68
#define NB 128

typedef float v4f __attribute__((ext_vector_type(4)));

__device__ inline void inv3x3(const double m[9], double inv[9], double* detOut) {
    double c00 =  m[4]*m[8] - m[5]*m[7];
    double c01 = -(m[3]*m[8] - m[5]*m[6]);
    double c02 =  m[3]*m[7] - m[4]*m[6];
    double det = m[0]*c00 + m[1]*c01 + m[2]*c02;
    double id = 1.0 / det;
    inv[0] = c00 * id;
    inv[1] = (m[2]*m[7] - m[1]*m[8]) * id;
    inv[2] = (m[1]*m[5] - m[2]*m[4]) * id;
    inv[3] = c01 * id;
    inv[4] = (m[0]*m[8] - m[2]*m[6]) * id;
    inv[5] = (m[2]*m[3] - m[0]*m[5]) * id;
    inv[6] = c02 * id;
    inv[7] = (m[1]*m[6] - m[0]*m[7]) * id;
    inv[8] = (m[0]*m[4] - m[1]*m[3]) * id;
    *detOut = det;
}

// Single fused kernel. 2048 blocks = 128 batches x 16 slabs.
// b = blockIdx & 127 so all 16 blocks of a batch share blockIdx%8 -> same XCD L2.
// Head-latency optimizations vs previous round:
//  (1) the 12 streaming Offset loads are issued BEFORE the keypoint/Newton head,
//      so their HBM latency hides under it (compiler can't hoist loads across
//      __syncthreads, so this must be source-level);
//  (2) the 17x68 LDS reduce uses 4 independent accumulators (dep chain 68->17);
//  (3) Newton polar: 6 iters, det-scaling (cbrt) only in the first 3 — scaled
//      iters equilibrate the spectrum, then plain X<-0.5(X+X^-T) is
//      quadratically convergent; error far below the bf16-level check.
__global__ __launch_bounds__(256) void fused_kernel(
    const float* __restrict__ Offset,
    const float* __restrict__ Posmap,
    const float* __restrict__ meanp,
    const int*   __restrict__ uv,
    float* __restrict__ out)
{
    const int b    = blockIdx.x & 127;
    const int slab = blockIdx.x >> 7;
    const int tid  = threadIdx.x;

    __shared__ double red[17][NKPT];
    __shared__ double res[17];
    __shared__ float  rtS[12];

    const size_t bbase = (size_t)b * 3 * HW;
    const int p0 = slab * 4096 + tid * 4;   // 4 groups, stride 1024 px

    // ---- phase 0: issue streaming loads early; latency hides under the head ----
    v4f a[3][4];
    #pragma unroll
    for (int g = 0; g < 4; ++g) {
        const int p = p0 + g * 1024;
        #pragma unroll
        for (int ch = 0; ch < 3; ++ch)
            a[ch][g] = __builtin_nontemporal_load((const v4f*)(Offset + bbase + (size_t)ch * HW + p));
    }

    // ---- phase 1: sufficient statistics over the 68 keypoints ----
    if (tid < NKPT) {
        const int r  = uv[2*tid],   c  = uv[2*tid+1];
        const int r0 = uv[0],       c0 = uv[1];
        const int p  = r  * 256 + c;
        const int p0k = r0 * 256 + c0;
        const float* offB = Offset + bbase;
        const float* posB = Posmap + bbase;
        double s[3], d[3], s0[3], d0[3];
        #pragma unroll
        for (int k = 0; k < 3; ++k) {
            s[k]  = (double)offB[k*HW + p  ] * 6.0 + (double)meanp[k*HW + p  ];
            d[k]  = (double)posB[k*HW + p  ];
            s0[k] = (double)offB[k*HW + p0k] * 6.0 + (double)meanp[k*HW + p0k];
            d0[k] = (double)posB[k*HW + p0k];
        }
        int q = 0;
        #pragma unroll
        for (int k = 0; k < 3; ++k) red[q++][tid] = s[k];
        #pragma unroll
        for (int k = 0; k < 3; ++k) red[q++][tid] = d[k];
        #pragma unroll
        for (int i = 0; i < 3; ++i)
            #pragma unroll
            for (int j = 0; j < 3; ++j) red[q++][tid] = s[i] * d[j];
        double ns2 = 0.0, nd2 = 0.0;
        #pragma unroll
        for (int k = 0; k < 3; ++k) {
            double e = s[k] - s0[k]; ns2 += e*e;
            double f = d[k] - d0[k]; nd2 += f*f;
        }
        red[q++][tid] = (ns2 > 0.0) ? sqrt(ns2) : 0.0;  // _safe_norm
        red[q++][tid] = (nd2 > 0.0) ? sqrt(nd2) : 0.0;
    }
    __syncthreads();
    if (tid < 17) {
        // 4 independent accumulators: dep chain 68 -> 17 (68 = 4*17 exact)
        double a0 = 0.0, a1 = 0.0, a2 = 0.0, a3 = 0.0;
        #pragma unroll
        for (int i = 0; i < NKPT; i += 4) {
            a0 += red[tid][i];
            a1 += red[tid][i+1];
            a2 += red[tid][i+2];
            a3 += red[tid][i+3];
        }
        res[tid] = (a0 + a1) + (a2 + a3);
    }
    __syncthreads();

    // ---- phase 2: thread 0 solves the 3x3 polar problem ----
    if (tid == 0) {
        const double sumS[3] = {res[0], res[1], res[2]};
        const double sumD[3] = {res[3], res[4], res[5]};
        double cross[9];
        #pragma unroll
        for (int k = 0; k < 9; ++k) cross[k] = res[6+k];
        const double s1 = res[15], s2 = res[16];
        const double scale = s2 / s1;
        double mS[3], mD[3];
        #pragma unroll
        for (int k = 0; k < 3; ++k) { mS[k] = sumS[k] / NKPT; mD[k] = sumD[k] / NKPT; }
        // Hm = (A - meanA)^T (dst - meanDst),  A = scale*src
        double Wm[9];
        #pragma unroll
        for (int i = 0; i < 3; ++i)
            #pragma unroll
            for (int j = 0; j < 3; ++j)
                Wm[i*3+j] = scale * (cross[i*3+j] - (double)NKPT * mS[i] * mD[j]);
        // Newton polar: 3 det-scaled iters, then 3 plain iters.
        #pragma unroll
        for (int it = 0; it < 6; ++it) {
            double inv[9], det;
            inv3x3(Wm, inv, &det);
            double g = 1.0, gi = 1.0;
            if (it < 3) { g = cbrt(fabs(det)); gi = 1.0 / g; }
            double Wn[9];
            #pragma unroll
            for (int r = 0; r < 3; ++r)
                #pragma unroll
                for (int c = 0; c < 3; ++c)
                    Wn[r*3+c] = 0.5 * (gi * Wm[r*3+c] + g * inv[c*3+r]);
            #pragma unroll
            for (int k = 0; k < 9; ++k) Wm[k] = Wn[k];
        }
        // R[e][d] = scale * Wm[d][e]  (R = V U^T = polar(Hm)^T)
        #pragma unroll
        for (int e = 0; e < 3; ++e)
            #pragma unroll
            for (int d = 0; d < 3; ++d)
                rtS[e*3+d] = (float)(scale * Wm[d*3+e]);
        #pragma unroll
        for (int e = 0; e < 3; ++e) {
            double acc = mD[e];
            #pragma unroll
            for (int d = 0; d < 3; ++d) acc -= scale * mS[d] * Wm[d*3+e];
            rtS[9+e] = (float)acc;
        }
    }
    __syncthreads();

    // ---- phase 3: apply R,t to this block's 4096-px slab ----
    const float r00 = rtS[0], r01 = rtS[1], r02 = rtS[2];
    const float r10 = rtS[3], r11 = rtS[4], r12 = rtS[5];
    const float r20 = rtS[6], r21 = rtS[7], r22 = rtS[8];
    const float t0  = rtS[9], t1  = rtS[10], t2 = rtS[11];

    v4f m[3][4];
    #pragma unroll
    for (int g = 0; g < 4; ++g) {
        const int p = p0 + g * 1024;
        #pragma unroll
        for (int ch = 0; ch < 3; ++ch)
            m[ch][g] = *(const v4f*)(meanp + (size_t)ch * HW + p);   // L2-resident
    }

    #pragma unroll
    for (int g = 0; g < 4; ++g) {
        const int p = p0 + g * 1024;
        v4f o0, o1, o2;
        #pragma unroll
        for (int L = 0; L < 4; ++L) {
            float x = fmaf(6.0f, a[0][g][L], m[0][g][L]);
            float y = fmaf(6.0f, a[1][g][L], m[1][g][L]);
            float z = fmaf(6.0f, a[2][g][L], m[2][g][L]);
            o0[L] = fmaf(r00, x, fmaf(r01, y, fmaf(r02, z, t0)));
            o1[L] = fmaf(r10, x, fmaf(r11, y, fmaf(r12, z, t1)));
            o2[L] = fmaf(r20, x, fmaf(r21, y, fmaf(r22, z, t2)));
        }
        __builtin_nontemporal_store(o0, (v4f*)(out + bbase + 0*HW + p));
        __builtin_nontemporal_store(o1, (v4f*)(out + bbase + 1*HW + p));
        __builtin_nontemporal_store(o2, (v4f*)(out + bbase + 2*HW + p));
    }
}

extern "C" void kernel_launch(void* const* d_in, const int* in_sizes, int n_in,
                              void* d_out, int out_size, void* d_ws, size_t ws_size,
                              hipStream_t stream) {
    const float* Offset = (const float*)d_in[0];
    const float* Posmap = (const float*)d_in[1];
    const float* meanp  = (const float*)d_in[2];
    const int*   uv     = (const int*)d_in[3];
    float* out = (float*)d_out;

    fused_kernel<<<NB * 16, 256, 0, stream>>>(Offset, Posmap, meanp, uv, out);
}